// Round 1
// baseline (287.505 us; speedup 1.0000x reference)
//
#include <hip/hip_runtime.h>
#include <math.h>

constexpr int B = 4, C = 64, H = 128, W = 128, KH = 3, KW = 3, K = 9, O = 64;
constexpr int HXW = H * W;

// weight[O][C][K] -> wt[K][C][O]
__global__ void wt_kernel(const float* __restrict__ weight, float* __restrict__ wt) {
    int idx = blockIdx.x * 256 + threadIdx.x;
    if (idx >= K * C * O) return;
    int o = idx & 63;
    int c = (idx >> 6) & 63;
    int k = idx >> 12;
    wt[idx] = weight[(o * C + c) * K + k];
}

// x[B][C][H][W] -> xt[B][H][W][C]
__global__ void xt_kernel(const float* __restrict__ x, float* __restrict__ xt) {
    int idx = blockIdx.x * 256 + threadIdx.x;   // B*H*W*C threads
    int c = idx & 63;
    int p = idx >> 6;                            // b*H*W + h*W + w
    int b = p >> 14;
    int hw = p & (HXW - 1);
    xt[idx] = x[(b * C + c) * HXW + hw];
}

template <bool NHWC>
__global__ __launch_bounds__(256) void mdcn_kernel(
        const float* __restrict__ x,       // NHWC xt (if NHWC) else NCHW x
        const float* __restrict__ offset,  // [B][2K][H][W]
        const float* __restrict__ mask,    // [B][K][H][W]
        const float* __restrict__ wt,      // [K][C][O]
        const float* __restrict__ bias,    // [O]
        float* __restrict__ out) {         // [B][O][H][W]
    int pid = blockIdx.x * 256 + threadIdx.x;   // B*H*W threads
    int b = pid >> 14;
    int hw = pid & (HXW - 1);
    int h = hw >> 7;
    int w = hw & 127;

    float acc[O];
#pragma unroll
    for (int o = 0; o < O; ++o) acc[o] = bias[o];

#pragma unroll 1
    for (int k = 0; k < K; ++k) {
        float offy = offset[((size_t)(b * 2 * K + 2 * k)) * HXW + hw];
        float offx = offset[((size_t)(b * 2 * K + 2 * k + 1)) * HXW + hw];
        float m    = mask[((size_t)(b * K + k)) * HXW + hw];

        float sy = (float)(h - 1 + k / 3) + offy;
        float sx = (float)(w - 1 + k % 3) + offx;
        float y0f = floorf(sy), x0f = floorf(sx);
        float wy = sy - y0f, wx = sx - x0f;
        int y0 = (int)y0f, x0 = (int)x0f;
        int y1 = y0 + 1, x1 = x0 + 1;

        bool vy0 = (y0 >= 0) & (y0 < H);
        bool vy1 = (y1 >= 0) & (y1 < H);
        bool vx0 = (x0 >= 0) & (x0 < W);
        bool vx1 = (x1 >= 0) & (x1 < W);

        // fold mask + validity into the 4 corner weights (branch-free)
        float w00 = (vy0 & vx0) ? (1.0f - wy) * (1.0f - wx) * m : 0.0f;
        float w01 = (vy0 & vx1) ? (1.0f - wy) * wx * m : 0.0f;
        float w10 = (vy1 & vx0) ? wy * (1.0f - wx) * m : 0.0f;
        float w11 = (vy1 & vx1) ? wy * wx * m : 0.0f;

        int y0c = min(max(y0, 0), H - 1), y1c = min(max(y1, 0), H - 1);
        int x0c = min(max(x0, 0), W - 1), x1c = min(max(x1, 0), W - 1);

        const float* wk = wt + k * C * O;

        if constexpr (NHWC) {
            const float* p00 = x + ((size_t)(b * H + y0c) * W + x0c) * C;
            const float* p01 = x + ((size_t)(b * H + y0c) * W + x1c) * C;
            const float* p10 = x + ((size_t)(b * H + y1c) * W + x0c) * C;
            const float* p11 = x + ((size_t)(b * H + y1c) * W + x1c) * C;
#pragma unroll 1
            for (int c0 = 0; c0 < C; c0 += 4) {
                float4 a00 = *(const float4*)(p00 + c0);
                float4 a01 = *(const float4*)(p01 + c0);
                float4 a10 = *(const float4*)(p10 + c0);
                float4 a11 = *(const float4*)(p11 + c0);
                float v0 = w00 * a00.x + w01 * a01.x + w10 * a10.x + w11 * a11.x;
                float v1 = w00 * a00.y + w01 * a01.y + w10 * a10.y + w11 * a11.y;
                float v2 = w00 * a00.z + w01 * a01.z + w10 * a10.z + w11 * a11.z;
                float v3 = w00 * a00.w + w01 * a01.w + w10 * a10.w + w11 * a11.w;
                const float* wr = wk + c0 * O;
#pragma unroll
                for (int o = 0; o < O; ++o) acc[o] = fmaf(wr[o], v0, acc[o]);
#pragma unroll
                for (int o = 0; o < O; ++o) acc[o] = fmaf(wr[O + o], v1, acc[o]);
#pragma unroll
                for (int o = 0; o < O; ++o) acc[o] = fmaf(wr[2 * O + o], v2, acc[o]);
#pragma unroll
                for (int o = 0; o < O; ++o) acc[o] = fmaf(wr[3 * O + o], v3, acc[o]);
            }
        } else {
            const float* p00 = x + (size_t)b * C * HXW + y0c * W + x0c;
            const float* p01 = x + (size_t)b * C * HXW + y0c * W + x1c;
            const float* p10 = x + (size_t)b * C * HXW + y1c * W + x0c;
            const float* p11 = x + (size_t)b * C * HXW + y1c * W + x1c;
#pragma unroll 1
            for (int c0 = 0; c0 < C; c0 += 4) {
                float v[4];
#pragma unroll
                for (int j = 0; j < 4; ++j) {
                    size_t cs = (size_t)(c0 + j) * HXW;
                    v[j] = w00 * p00[cs] + w01 * p01[cs] + w10 * p10[cs] + w11 * p11[cs];
                }
                const float* wr = wk + c0 * O;
#pragma unroll
                for (int j = 0; j < 4; ++j)
#pragma unroll
                    for (int o = 0; o < O; ++o) acc[o] = fmaf(wr[j * O + o], v[j], acc[o]);
            }
        }
    }

#pragma unroll
    for (int o = 0; o < O; ++o) out[((size_t)(b * O + o)) * HXW + hw] = acc[o];
}

extern "C" void kernel_launch(void* const* d_in, const int* in_sizes, int n_in,
                              void* d_out, int out_size, void* d_ws, size_t ws_size,
                              hipStream_t stream) {
    const float* x      = (const float*)d_in[0];
    const float* offset = (const float*)d_in[1];
    const float* mask   = (const float*)d_in[2];
    const float* weight = (const float*)d_in[3];
    const float* bias   = (const float*)d_in[4];
    float* out = (float*)d_out;

    float* wt = (float*)d_ws;
    float* xt = wt + K * C * O;
    size_t need = (size_t)(K * C * O + (size_t)B * H * W * C) * sizeof(float);

    wt_kernel<<<(K * C * O + 255) / 256, 256, 0, stream>>>(weight, wt);

    if (ws_size >= need) {
        xt_kernel<<<(B * H * W * C) / 256, 256, 0, stream>>>(x, xt);
        mdcn_kernel<true><<<(B * HXW) / 256, 256, 0, stream>>>(xt, offset, mask, wt, bias, out);
    } else {
        mdcn_kernel<false><<<(B * HXW) / 256, 256, 0, stream>>>(x, offset, mask, wt, bias, out);
    }
}

// Round 2
// 113.524 us; speedup vs baseline: 2.5325x; 2.5325x over previous
//
#include <hip/hip_runtime.h>
#include <math.h>

constexpr int B = 4, C = 64, H = 128, W = 128, K = 9, O = 64;
constexpr int HXW = H * W;
constexpr int C4 = C / 4;

// weight[O][C][K] -> wt[K][C][O]
__global__ void wt_kernel(const float* __restrict__ weight, float* __restrict__ wt) {
    int idx = blockIdx.x * 256 + threadIdx.x;
    if (idx >= K * C * O) return;
    int o = idx & 63;
    int c = (idx >> 6) & 63;
    int k = idx >> 12;
    wt[idx] = weight[(o * C + c) * K + k];
}

// x[B][C][H][W] -> xq[B][C/4][H][W][4]  (stored as float4)
__global__ void xq_kernel(const float* __restrict__ x, float4* __restrict__ xq) {
    int idx = blockIdx.x * 256 + threadIdx.x;   // (b, c4, hw) = B*16*HXW threads
    int hw = idx & (HXW - 1);
    int t = idx >> 14;
    int c4 = t & 15;
    int b = t >> 4;
    const float* src = x + ((size_t)(b * C + c4 * 4)) * HXW + hw;
    float4 v;
    v.x = src[0];
    v.y = src[HXW];
    v.z = src[2 * HXW];
    v.w = src[3 * HXW];
    xq[idx] = v;
}

// 512 blocks x 256 threads; block = 128 pixels x 2 output-halves.
// slab = bid & 7 -> (batch, half-image): keeps each XCD's gathers in its own L2.
__global__ __launch_bounds__(256) void mdcn_v2(
        const float4* __restrict__ xq,     // [B][C4][H][W] float4
        const float* __restrict__ offset,  // [B][2K][H][W]
        const float* __restrict__ mask,    // [B][K][H][W]
        const float* __restrict__ wt,      // [K][C][O]
        const float* __restrict__ bias,    // [O]
        float* __restrict__ out) {         // [B][O][H][W]
    int bid = blockIdx.x;
    int slab = bid & 7;
    int within = bid >> 3;                  // 0..63
    int tid = threadIdx.x;
    int lpix = tid & 127;
    int oh = tid >> 7;                      // 0 or 1, wave-uniform
    int oh32 = __builtin_amdgcn_readfirstlane(oh << 5);

    int pid = slab * 8192 + within * 128 + lpix;
    int b = pid >> 14;
    int hw = pid & (HXW - 1);
    int h = hw >> 7;
    int w = hw & 127;

    float acc[32];
#pragma unroll
    for (int o = 0; o < 32; ++o) acc[o] = bias[oh32 + o];

    size_t xbase = (size_t)b * C4 * HXW;    // float4 units

#pragma unroll 1
    for (int k = 0; k < K; ++k) {
        float offy = offset[((size_t)(b * 2 * K + 2 * k)) * HXW + hw];
        float offx = offset[((size_t)(b * 2 * K + 2 * k + 1)) * HXW + hw];
        float m    = mask[((size_t)(b * K + k)) * HXW + hw];

        float sy = (float)(h - 1 + k / 3) + offy;
        float sx = (float)(w - 1 + k % 3) + offx;
        float y0f = floorf(sy), x0f = floorf(sx);
        float wy = sy - y0f, wx = sx - x0f;
        int y0 = (int)y0f, x0 = (int)x0f;
        int y1 = y0 + 1, x1 = x0 + 1;

        bool vy0 = (y0 >= 0) & (y0 < H);
        bool vy1 = (y1 >= 0) & (y1 < H);
        bool vx0 = (x0 >= 0) & (x0 < W);
        bool vx1 = (x1 >= 0) & (x1 < W);

        float w00 = (vy0 & vx0) ? (1.0f - wy) * (1.0f - wx) * m : 0.0f;
        float w01 = (vy0 & vx1) ? (1.0f - wy) * wx * m : 0.0f;
        float w10 = (vy1 & vx0) ? wy * (1.0f - wx) * m : 0.0f;
        float w11 = (vy1 & vx1) ? wy * wx * m : 0.0f;

        int y0c = min(max(y0, 0), H - 1), y1c = min(max(y1, 0), H - 1);
        int x0c = min(max(x0, 0), W - 1), x1c = min(max(x1, 0), W - 1);

        int p00 = y0c * W + x0c, p01 = y0c * W + x1c;
        int p10 = y1c * W + x0c, p11 = y1c * W + x1c;

        const float* wk = wt + k * C * O + oh32;

#pragma unroll 2
        for (int c4 = 0; c4 < C4; ++c4) {
            size_t cs = xbase + (size_t)c4 * HXW;
            float4 a00 = xq[cs + p00];
            float4 a01 = xq[cs + p01];
            float4 a10 = xq[cs + p10];
            float4 a11 = xq[cs + p11];
            float v0 = w00 * a00.x + w01 * a01.x + w10 * a10.x + w11 * a11.x;
            float v1 = w00 * a00.y + w01 * a01.y + w10 * a10.y + w11 * a11.y;
            float v2 = w00 * a00.z + w01 * a01.z + w10 * a10.z + w11 * a11.z;
            float v3 = w00 * a00.w + w01 * a01.w + w10 * a10.w + w11 * a11.w;
            const float* wr = wk + (c4 * 4) * O;
#pragma unroll
            for (int o = 0; o < 32; ++o) acc[o] = fmaf(wr[o], v0, acc[o]);
#pragma unroll
            for (int o = 0; o < 32; ++o) acc[o] = fmaf(wr[O + o], v1, acc[o]);
#pragma unroll
            for (int o = 0; o < 32; ++o) acc[o] = fmaf(wr[2 * O + o], v2, acc[o]);
#pragma unroll
            for (int o = 0; o < 32; ++o) acc[o] = fmaf(wr[3 * O + o], v3, acc[o]);
        }
    }

    size_t ob = ((size_t)(b * O + oh32)) * HXW + hw;
#pragma unroll
    for (int o = 0; o < 32; ++o) out[ob + (size_t)o * HXW] = acc[o];
}

// Fallback (ws too small): direct NCHW version from round 1 (proven correct).
__global__ __launch_bounds__(256) void mdcn_nchw(
        const float* __restrict__ x, const float* __restrict__ offset,
        const float* __restrict__ mask, const float* __restrict__ wt,
        const float* __restrict__ bias, float* __restrict__ out) {
    int pid = blockIdx.x * 256 + threadIdx.x;
    int b = pid >> 14;
    int hw = pid & (HXW - 1);
    int h = hw >> 7;
    int w = hw & 127;
    float acc[O];
#pragma unroll
    for (int o = 0; o < O; ++o) acc[o] = bias[o];
#pragma unroll 1
    for (int k = 0; k < K; ++k) {
        float offy = offset[((size_t)(b * 2 * K + 2 * k)) * HXW + hw];
        float offx = offset[((size_t)(b * 2 * K + 2 * k + 1)) * HXW + hw];
        float m    = mask[((size_t)(b * K + k)) * HXW + hw];
        float sy = (float)(h - 1 + k / 3) + offy;
        float sx = (float)(w - 1 + k % 3) + offx;
        float y0f = floorf(sy), x0f = floorf(sx);
        float wy = sy - y0f, wx = sx - x0f;
        int y0 = (int)y0f, x0 = (int)x0f;
        int y1 = y0 + 1, x1 = x0 + 1;
        bool vy0 = (y0 >= 0) & (y0 < H), vy1 = (y1 >= 0) & (y1 < H);
        bool vx0 = (x0 >= 0) & (x0 < W), vx1 = (x1 >= 0) & (x1 < W);
        float w00 = (vy0 & vx0) ? (1.0f - wy) * (1.0f - wx) * m : 0.0f;
        float w01 = (vy0 & vx1) ? (1.0f - wy) * wx * m : 0.0f;
        float w10 = (vy1 & vx0) ? wy * (1.0f - wx) * m : 0.0f;
        float w11 = (vy1 & vx1) ? wy * wx * m : 0.0f;
        int y0c = min(max(y0, 0), H - 1), y1c = min(max(y1, 0), H - 1);
        int x0c = min(max(x0, 0), W - 1), x1c = min(max(x1, 0), W - 1);
        const float* p00 = x + (size_t)b * C * HXW + y0c * W + x0c;
        const float* p01 = x + (size_t)b * C * HXW + y0c * W + x1c;
        const float* p10 = x + (size_t)b * C * HXW + y1c * W + x0c;
        const float* p11 = x + (size_t)b * C * HXW + y1c * W + x1c;
        const float* wk = wt + k * C * O;
#pragma unroll 1
        for (int c0 = 0; c0 < C; c0 += 4) {
            float v[4];
#pragma unroll
            for (int j = 0; j < 4; ++j) {
                size_t cs = (size_t)(c0 + j) * HXW;
                v[j] = w00 * p00[cs] + w01 * p01[cs] + w10 * p10[cs] + w11 * p11[cs];
            }
            const float* wr = wk + c0 * O;
#pragma unroll
            for (int j = 0; j < 4; ++j)
#pragma unroll
                for (int o = 0; o < O; ++o) acc[o] = fmaf(wr[j * O + o], v[j], acc[o]);
        }
    }
#pragma unroll
    for (int o = 0; o < O; ++o) out[((size_t)(b * O + o)) * HXW + hw] = acc[o];
}

extern "C" void kernel_launch(void* const* d_in, const int* in_sizes, int n_in,
                              void* d_out, int out_size, void* d_ws, size_t ws_size,
                              hipStream_t stream) {
    const float* x      = (const float*)d_in[0];
    const float* offset = (const float*)d_in[1];
    const float* mask   = (const float*)d_in[2];
    const float* weight = (const float*)d_in[3];
    const float* bias   = (const float*)d_in[4];
    float* out = (float*)d_out;

    float* wt = (float*)d_ws;
    float4* xq = (float4*)(wt + K * C * O);
    size_t need = (size_t)(K * C * O) * sizeof(float) + (size_t)B * C4 * HXW * sizeof(float4);

    wt_kernel<<<(K * C * O + 255) / 256, 256, 0, stream>>>(weight, wt);

    if (ws_size >= need) {
        xq_kernel<<<(B * C4 * HXW) / 256, 256, 0, stream>>>(x, xq);
        mdcn_v2<<<512, 256, 0, stream>>>(xq, offset, mask, wt, bias, out);
    } else {
        mdcn_nchw<<<(B * HXW) / 256, 256, 0, stream>>>(x, offset, mask, wt, bias, out);
    }
}

// Round 3
// 98.626 us; speedup vs baseline: 2.9151x; 1.1511x over previous
//
#include <hip/hip_runtime.h>
#include <hip/hip_bf16.h>
#include <math.h>

constexpr int B = 4, C = 64, H = 128, W = 128, K = 9, O = 64;
constexpr int HXW = H * W;
constexpr int C4 = C / 4;

typedef short short8 __attribute__((ext_vector_type(8)));
typedef float f32x4 __attribute__((ext_vector_type(4)));

static __device__ __forceinline__ short f2bf(float v) {
    __hip_bfloat16 h = __float2bfloat16(v);
    return (short)__builtin_bit_cast(unsigned short, h);
}

// weight[O][C][K] -> wt[K][C][O]  (fp32, for fallback)
__global__ void wt_kernel(const float* __restrict__ weight, float* __restrict__ wt) {
    int idx = blockIdx.x * 256 + threadIdx.x;
    if (idx >= K * C * O) return;
    int o = idx & 63;
    int c = (idx >> 6) & 63;
    int k = idx >> 12;
    wt[idx] = weight[(o * C + c) * K + k];
}

// weight[O][C][K] -> wtb[K][O][C]  (bf16 bits)
__global__ void wtb_kernel(const float* __restrict__ weight, short* __restrict__ wtb) {
    int idx = blockIdx.x * 256 + threadIdx.x;
    if (idx >= K * O * C) return;
    int c = idx & 63;
    int o = (idx >> 6) & 63;
    int k = idx >> 12;
    wtb[idx] = f2bf(weight[(o * C + c) * K + k]);
}

// x[B][C][H][W] -> xq[B][C/4][H][W][4]  (float4)
__global__ void xq_kernel(const float* __restrict__ x, float4* __restrict__ xq) {
    int idx = blockIdx.x * 256 + threadIdx.x;
    int hw = idx & (HXW - 1);
    int t = idx >> 14;
    int c4 = t & 15;
    int b = t >> 4;
    const float* src = x + ((size_t)(b * C + c4 * 4)) * HXW + hw;
    float4 v;
    v.x = src[0];
    v.y = src[HXW];
    v.z = src[2 * HXW];
    v.w = src[3 * HXW];
    xq[idx] = v;
}

// 512 blocks x 256 threads. Block = 128 pixels; 4 waves x (32 px, 64 out).
// slab = bid & 7 -> (batch, half-image) so each XCD's gathers stay in its L2.
__global__ __launch_bounds__(256, 3) void mdcn_mfma(
        const float4* __restrict__ xq,     // [B][C4][H][W] float4
        const float* __restrict__ offset,  // [B][2K][H][W]
        const float* __restrict__ mask,    // [B][K][H][W]
        const short* __restrict__ wtb,     // [K][O][C] bf16
        const float* __restrict__ bias,    // [O]
        float* __restrict__ out) {         // [B][O][H][W]
    __shared__ short A[2][128 * 64];       // 2 x 16 KB, XOR-swizzled 16B slots

    int bid = blockIdx.x;
    int slab = bid & 7;
    int within = bid >> 3;                  // 0..63
    int tid = threadIdx.x;
    int p = tid >> 1;                       // block-local pixel 0..127
    int half = tid & 1;                     // channel half
    int pid = slab * 8192 + within * 128 + p;
    int b = pid >> 14;
    int hw = pid & (HXW - 1);
    int h = hw >> 7;
    int w = hw & 127;

    int lane = tid & 63;
    int wid = tid >> 6;                     // wave id 0..3 -> px [wid*32, wid*32+32)
    int ml = lane & 15;
    int kg = lane >> 4;

    f32x4 acc[2][4];
#pragma unroll
    for (int nf = 0; nf < 4; ++nf) {
        float bv = bias[nf * 16 + ml];
        acc[0][nf] = (f32x4){bv, bv, bv, bv};
        acc[1][nf] = (f32x4){bv, bv, bv, bv};
    }
    // bias added twice otherwise: zero one of the mf halves' init? No: acc[0],acc[1]
    // are different pixel rows of the SAME output -> each needs bias. OK.

    size_t xbase = (size_t)b * C4 * HXW;    // float4 units

#pragma unroll 1
    for (int k = 0; k < K; ++k) {
        // ---- B fragments for this tap: wtb[k][o][ch], lane holds o=nf*16+ml, ch=ks*32+kg*8.. +8
        short8 bf[2][4];
#pragma unroll
        for (int ks = 0; ks < 2; ++ks)
#pragma unroll
            for (int nf = 0; nf < 4; ++nf)
                bf[ks][nf] = *(const short8*)(wtb + ((k * O + nf * 16 + ml) * C + ks * 32 + kg * 8));

        // ---- sampling: this thread does pixel p, channels [half*32, half*32+32)
        float offy = offset[((size_t)(b * 2 * K + 2 * k)) * HXW + hw];
        float offx = offset[((size_t)(b * 2 * K + 2 * k + 1)) * HXW + hw];
        float m    = mask[((size_t)(b * K + k)) * HXW + hw];

        float sy = (float)(h - 1 + k / 3) + offy;
        float sx = (float)(w - 1 + k % 3) + offx;
        float y0f = floorf(sy), x0f = floorf(sx);
        float wy = sy - y0f, wx = sx - x0f;
        int y0 = (int)y0f, x0 = (int)x0f;
        int y1 = y0 + 1, x1 = x0 + 1;
        bool vy0 = (y0 >= 0) & (y0 < H), vy1 = (y1 >= 0) & (y1 < H);
        bool vx0 = (x0 >= 0) & (x0 < W), vx1 = (x1 >= 0) & (x1 < W);
        float w00 = (vy0 & vx0) ? (1.0f - wy) * (1.0f - wx) * m : 0.0f;
        float w01 = (vy0 & vx1) ? (1.0f - wy) * wx * m : 0.0f;
        float w10 = (vy1 & vx0) ? wy * (1.0f - wx) * m : 0.0f;
        float w11 = (vy1 & vx1) ? wy * wx * m : 0.0f;
        int y0c = min(max(y0, 0), H - 1), y1c = min(max(y1, 0), H - 1);
        int x0c = min(max(x0, 0), W - 1), x1c = min(max(x1, 0), W - 1);
        int p00 = y0c * W + x0c, p01 = y0c * W + x1c;
        int p10 = y1c * W + x0c, p11 = y1c * W + x1c;

        short* Ab = &A[k & 1][0];
#pragma unroll
        for (int j = 0; j < 4; ++j) {       // j = 8-channel group within this half
            short8 pk;
#pragma unroll
            for (int jj = 0; jj < 2; ++jj) {
                int c4 = half * 8 + j * 2 + jj;
                size_t cs = xbase + (size_t)c4 * HXW;
                float4 a00 = xq[cs + p00];
                float4 a01 = xq[cs + p01];
                float4 a10 = xq[cs + p10];
                float4 a11 = xq[cs + p11];
                pk[jj * 4 + 0] = f2bf(w00 * a00.x + w01 * a01.x + w10 * a10.x + w11 * a11.x);
                pk[jj * 4 + 1] = f2bf(w00 * a00.y + w01 * a01.y + w10 * a10.y + w11 * a11.y);
                pk[jj * 4 + 2] = f2bf(w00 * a00.z + w01 * a01.z + w10 * a10.z + w11 * a11.z);
                pk[jj * 4 + 3] = f2bf(w00 * a00.w + w01 * a01.w + w10 * a10.w + w11 * a11.w);
            }
            int slot = half * 4 + j;
            *(short8*)(Ab + p * 64 + ((slot ^ (p & 7)) << 3)) = pk;
        }

        __syncthreads();

        // ---- MFMA: wave `wid` computes px [wid*32, +32) x all 64 outputs
#pragma unroll
        for (int ks = 0; ks < 2; ++ks) {
            short8 af[2];
#pragma unroll
            for (int mf = 0; mf < 2; ++mf) {
                int px = wid * 32 + mf * 16 + ml;
                int slot = ks * 4 + kg;
                af[mf] = *(const short8*)(Ab + px * 64 + ((slot ^ (px & 7)) << 3));
            }
#pragma unroll
            for (int mf = 0; mf < 2; ++mf)
#pragma unroll
                for (int nf = 0; nf < 4; ++nf)
                    acc[mf][nf] = __builtin_amdgcn_mfma_f32_16x16x32_bf16(
                        af[mf], bf[ks][nf], acc[mf][nf], 0, 0, 0);
        }
        // no second barrier: next tap writes the OTHER LDS buffer
    }

    // ---- store: D row(px) = (lane>>4)*4+reg, col(o) = lane&15
    int hwb = (slab & 1) * 8192 + within * 128 + wid * 32;
#pragma unroll
    for (int mf = 0; mf < 2; ++mf)
#pragma unroll
        for (int nf = 0; nf < 4; ++nf) {
            size_t ob = ((size_t)(b * O + nf * 16 + ml)) * HXW + hwb + mf * 16 + kg * 4;
#pragma unroll
            for (int r = 0; r < 4; ++r)
                out[ob + r] = acc[mf][nf][r];
        }
}

// Fallback (ws too small): direct NCHW fp32 (proven in round 1).
__global__ __launch_bounds__(256) void mdcn_nchw(
        const float* __restrict__ x, const float* __restrict__ offset,
        const float* __restrict__ mask, const float* __restrict__ wt,
        const float* __restrict__ bias, float* __restrict__ out) {
    int pid = blockIdx.x * 256 + threadIdx.x;
    int b = pid >> 14;
    int hw = pid & (HXW - 1);
    int h = hw >> 7;
    int w = hw & 127;
    float acc[O];
#pragma unroll
    for (int o = 0; o < O; ++o) acc[o] = bias[o];
#pragma unroll 1
    for (int k = 0; k < K; ++k) {
        float offy = offset[((size_t)(b * 2 * K + 2 * k)) * HXW + hw];
        float offx = offset[((size_t)(b * 2 * K + 2 * k + 1)) * HXW + hw];
        float m    = mask[((size_t)(b * K + k)) * HXW + hw];
        float sy = (float)(h - 1 + k / 3) + offy;
        float sx = (float)(w - 1 + k % 3) + offx;
        float y0f = floorf(sy), x0f = floorf(sx);
        float wy = sy - y0f, wx = sx - x0f;
        int y0 = (int)y0f, x0 = (int)x0f;
        int y1 = y0 + 1, x1 = x0 + 1;
        bool vy0 = (y0 >= 0) & (y0 < H), vy1 = (y1 >= 0) & (y1 < H);
        bool vx0 = (x0 >= 0) & (x0 < W), vx1 = (x1 >= 0) & (x1 < W);
        float w00 = (vy0 & vx0) ? (1.0f - wy) * (1.0f - wx) * m : 0.0f;
        float w01 = (vy0 & vx1) ? (1.0f - wy) * wx * m : 0.0f;
        float w10 = (vy1 & vx0) ? wy * (1.0f - wx) * m : 0.0f;
        float w11 = (vy1 & vx1) ? wy * wx * m : 0.0f;
        int y0c = min(max(y0, 0), H - 1), y1c = min(max(y1, 0), H - 1);
        int x0c = min(max(x0, 0), W - 1), x1c = min(max(x1, 0), W - 1);
        const float* p00 = x + (size_t)b * C * HXW + y0c * W + x0c;
        const float* p01 = x + (size_t)b * C * HXW + y0c * W + x1c;
        const float* p10 = x + (size_t)b * C * HXW + y1c * W + x0c;
        const float* p11 = x + (size_t)b * C * HXW + y1c * W + x1c;
        const float* wk = wt + k * C * O;
#pragma unroll 1
        for (int c0 = 0; c0 < C; c0 += 4) {
            float v[4];
#pragma unroll
            for (int j = 0; j < 4; ++j) {
                size_t cs = (size_t)(c0 + j) * HXW;
                v[j] = w00 * p00[cs] + w01 * p01[cs] + w10 * p10[cs] + w11 * p11[cs];
            }
            const float* wr = wk + c0 * O;
#pragma unroll
            for (int j = 0; j < 4; ++j)
#pragma unroll
                for (int o = 0; o < O; ++o) acc[o] = fmaf(wr[j * O + o], v[j], acc[o]);
        }
    }
#pragma unroll
    for (int o = 0; o < O; ++o) out[((size_t)(b * O + o)) * HXW + hw] = acc[o];
}

extern "C" void kernel_launch(void* const* d_in, const int* in_sizes, int n_in,
                              void* d_out, int out_size, void* d_ws, size_t ws_size,
                              hipStream_t stream) {
    const float* x      = (const float*)d_in[0];
    const float* offset = (const float*)d_in[1];
    const float* mask   = (const float*)d_in[2];
    const float* weight = (const float*)d_in[3];
    const float* bias   = (const float*)d_in[4];
    float* out = (float*)d_out;

    float* wt   = (float*)d_ws;                                   // 147456 B
    short* wtb  = (short*)((char*)d_ws + 147456);                 // 73728 B
    float4* xq  = (float4*)((char*)d_ws + 147456 + 73728);        // 16.8 MB
    size_t need = 147456 + 73728 + (size_t)B * C4 * HXW * sizeof(float4);

    if (ws_size >= need) {
        wtb_kernel<<<(K * O * C + 255) / 256, 256, 0, stream>>>(weight, wtb);
        xq_kernel<<<(B * C4 * HXW) / 256, 256, 0, stream>>>(x, xq);
        mdcn_mfma<<<512, 256, 0, stream>>>(xq, offset, mask, wtb, bias, out);
    } else {
        wt_kernel<<<(K * C * O + 255) / 256, 256, 0, stream>>>(weight, wt);
        mdcn_nchw<<<(B * HXW) / 256, 256, 0, stream>>>(x, offset, mask, wt, bias, out);
    }
}